// Round 9
// baseline (1672.719 us; speedup 1.0000x reference)
//
#include <hip/hip_runtime.h>

#define N_NODES 50000
#define N_EDGES 800000
#define NFEAT   512
#define NHID    256
#define NCLASS  64

#define MTILES  ((N_NODES + 63) / 64)     // 782

#define BKT  80                            // nodes per bucket
#define NB   625                           // buckets (625*80 = 50000 exact)
#define NBB  128                           // bin blocks per layer
#define EPB  6250                          // edges per bin block (128*6250 = 800000)

typedef short short8  __attribute__((ext_vector_type(8)));
typedef float floatx4 __attribute__((ext_vector_type(4)));

__device__ inline short f2bf(float f) {
    unsigned u = __builtin_bit_cast(unsigned, f);
    u += 0x7FFF + ((u >> 16) & 1);   // round-to-nearest-even
    return (short)(u >> 16);
}
__device__ inline float bf2f(short v) {
    unsigned u = ((unsigned)(unsigned short)v) << 16;
    return __builtin_bit_cast(float, u);
}
// packed edge: low 16 = src node id (<65536), high 16 = bf16 weight
__device__ inline int pack_edge(int src, float w) {
    return (src & 0xFFFF) | ((int)(unsigned short)f2bf(w) << 16);
}

// ---------------- weight casts ----------------
__global__ __launch_bounds__(256) void cast_w1t_kernel(const float* __restrict__ W1,
                                                       short* __restrict__ Wt) {
    const int k = blockIdx.x, n = threadIdx.x;
    Wt[n * NFEAT + k] = f2bf(W1[k * NHID + n]);
}
__global__ __launch_bounds__(256) void cast_w2t_kernel(const float* __restrict__ W2,
                                                       short* __restrict__ W2t) {
    const int n = blockIdx.x, k = threadIdx.x;
    W2t[n * NHID + k] = f2bf(W2[k * NCLASS + n]);
}

// ---------------- GEMM1 (LDS-tiled MFMA, fused fp32->bf16 A-cast) --------------------
__global__ __launch_bounds__(256) void gemm1_mfma_kernel(const float* __restrict__ x,
                                                         const short* __restrict__ Wt,
                                                         short* __restrict__ h0b) {
    __shared__ short As[64 * 32];
    __shared__ short Bs[256 * 32];
    const int tid  = threadIdx.x;
    const int wave = tid >> 6, lane = tid & 63;
    const int mlo  = lane & 15, q = lane >> 4;
    const int m0   = blockIdx.x * 64;

    const int ar  = tid >> 2;
    const int acg = (tid & 3) * 8;
    int arow = m0 + ar; if (arow >= N_NODES) arow = N_NODES - 1;
    const float* aptr = x + (size_t)arow * NFEAT + acg;

    floatx4 acc[4][4] = {};

    for (int kc = 0; kc < NFEAT; kc += 32) {
        float4 a0 = *(const float4*)(aptr + kc);
        float4 a1 = *(const float4*)(aptr + kc + 4);
        short8 ap;
        ap[0]=f2bf(a0.x); ap[1]=f2bf(a0.y); ap[2]=f2bf(a0.z); ap[3]=f2bf(a0.w);
        ap[4]=f2bf(a1.x); ap[5]=f2bf(a1.y); ap[6]=f2bf(a1.z); ap[7]=f2bf(a1.w);
        *(short8*)&As[ar * 32 + acg] = ap;
        #pragma unroll
        for (int it = 0; it < 4; ++it) {
            int g = it * 256 + tid;
            *(short8*)&Bs[g * 8] =
                *(const short8*)(Wt + (size_t)(g >> 2) * NFEAT + kc + (g & 3) * 8);
        }
        __syncthreads();

        short8 af[4], bfr[4];
        #pragma unroll
        for (int t = 0; t < 4; ++t)
            af[t] = *(const short8*)&As[(t * 16 + mlo) * 32 + q * 8];
        #pragma unroll
        for (int u = 0; u < 4; ++u)
            bfr[u] = *(const short8*)&Bs[(wave * 64 + u * 16 + mlo) * 32 + q * 8];
        #pragma unroll
        for (int t = 0; t < 4; ++t)
            #pragma unroll
            for (int u = 0; u < 4; ++u)
                acc[t][u] = __builtin_amdgcn_mfma_f32_16x16x32_bf16(af[t], bfr[u], acc[t][u], 0, 0, 0);
        __syncthreads();
    }

    #pragma unroll
    for (int t = 0; t < 4; ++t)
        #pragma unroll
        for (int r = 0; r < 4; ++r) {
            int row = m0 + t * 16 + q * 4 + r;
            if (row < N_NODES)
                #pragma unroll
                for (int u = 0; u < 4; ++u)
                    h0b[(size_t)row * NHID + wave * 64 + u * 16 + mlo] = f2bf(acc[t][u][r]);
        }
}

// ---------------- bucket-bin pass A: per-block LDS histogram over 625 buckets --------
__global__ __launch_bounds__(256) void bh_kernel(const int* __restrict__ ed0,
                                                 const int* __restrict__ ed1,
                                                 int* __restrict__ hist) {
    __shared__ int h[NB];
    const int blk = blockIdx.x;            // 0..255
    const int layer = blk >> 7, i = blk & 127;
    const int* ed = layer ? ed1 : ed0;
    for (int t = threadIdx.x; t < NB; t += 256) h[t] = 0;
    __syncthreads();
    const int e0 = i * EPB;
    for (int it = threadIdx.x; it < EPB; it += 256)
        atomicAdd(&h[ed[e0 + it] / BKT], 1);          // LDS atomic
    __syncthreads();
    int* row = hist + ((size_t)layer * NBB + i) * NB;
    for (int t = threadIdx.x; t < NB; t += 256) row[t] = h[t];
}

// ---- pass B: per-bucket exclusive scan over the 128 bin blocks -> offT + totals -----
__global__ __launch_bounds__(256) void bscan_kernel(const int* __restrict__ hist,
                                                    int* __restrict__ offT,
                                                    int* __restrict__ tot) {
    __shared__ int s[128];
    const int blk = blockIdx.x;            // 0..1249
    const int layer = blk >= NB ? 1 : 0;
    const int b = blk - layer * NB;
    const int t = threadIdx.x;
    int v = 0;
    if (t < 128) { v = hist[((size_t)layer * NBB + t) * NB + b]; s[t] = v; }
    __syncthreads();
    for (int off = 1; off < 128; off <<= 1) {
        int a = (t >= off && t < 128) ? s[t - off] : 0;
        __syncthreads();
        if (t < 128) s[t] += a;
        __syncthreads();
    }
    if (t < 128) offT[((size_t)layer * NB + b) * NBB + t] = s[t] - v;   // exclusive
    if (t == 0)  tot[layer * NB + b] = s[127];
}

// ---- pass C: exclusive scan of 625 bucket totals -> base[626] per layer -------------
__global__ __launch_bounds__(256) void btop_kernel(const int* __restrict__ tot,
                                                   int* __restrict__ base) {
    __shared__ int s[256];
    __shared__ int carry;
    const int layer = blockIdx.x;
    const int t = threadIdx.x;
    if (t == 0) carry = 0;
    __syncthreads();
    for (int c0 = 0; c0 < NB; c0 += 256) {
        int idx = c0 + t;
        int v = (idx < NB) ? tot[layer * NB + idx] : 0;
        s[t] = v;
        __syncthreads();
        for (int off = 1; off < 256; off <<= 1) {
            int a = (t >= off) ? s[t - off] : 0;
            __syncthreads();
            s[t] += a;
            __syncthreads();
        }
        if (idx < NB) base[layer * (NB + 1) + idx] = carry + s[t] - v;
        __syncthreads();
        if (t == 0) carry += s[255];
        __syncthreads();
    }
    if (t == 0) base[layer * (NB + 1) + NB] = carry;   // = 800000
}

// ---- pass D: scatter into bucket-grouped array. Runs of ~10 records per (blk,bucket)
// keep writes mostly full-line; positions unique by construction. rec = (src|w, dstlo)
__global__ __launch_bounds__(256) void bscatter_kernel(
        const int* __restrict__ es0, const int* __restrict__ ed0, const float* __restrict__ ew0,
        const int* __restrict__ es1, const int* __restrict__ ed1, const float* __restrict__ ew1,
        const int* __restrict__ offT, const int* __restrict__ base,
        int2* __restrict__ binned0, int2* __restrict__ binned1) {
    __shared__ int cur[NB];
    const int blk = blockIdx.x;            // 0..255
    const int layer = blk >> 7, i = blk & 127;
    const int*   es = layer ? es1 : es0;
    const int*   ed = layer ? ed1 : ed0;
    const float* ew = layer ? ew1 : ew0;
    int2* binned = layer ? binned1 : binned0;
    for (int b = threadIdx.x; b < NB; b += 256)
        cur[b] = base[layer * (NB + 1) + b] + offT[((size_t)layer * NB + b) * NBB + i];
    __syncthreads();
    const int e0 = i * EPB;
    for (int it = threadIdx.x; it < EPB; it += 256) {
        int e = e0 + it;
        int d = ed[e];
        int b = d / BKT;
        int p = atomicAdd(&cur[b], 1);                 // LDS atomic
        binned[p] = make_int2(pack_edge(es[e], ew[e]), d - b * BKT);
    }
}

// ---------------- SpMM1: block per (bucket, 64-feat slice), LDS accumulator ----------
// Block exclusively owns agg0[bucket rows][slice cols] -> sequential full-line stores.
__global__ __launch_bounds__(256) void spmm1_bucket_kernel(const int* __restrict__ base,
                                                           const int2* __restrict__ binned,
                                                           const short* __restrict__ h0b,
                                                           float* __restrict__ agg0) {
    __shared__ float acc[BKT * 64];   // 20 KB
    const int blk = blockIdx.x;       // 0..2499
    const int b = blk >> 2, sl = blk & 3;
    const int tid = threadIdx.x, lane = tid & 63, wv = tid >> 6;
    for (int t = tid; t < BKT * 64; t += 256) acc[t] = 0.f;
    __syncthreads();

    const int st = base[b], en = base[b + 1];
    const short* hsl = h0b + sl * 64 + lane;

    int j = st + wv;
    int2 rec0 = {0,0}, rec1 = {0,0};
    short hv0 = 0;
    if (j < en)     rec0 = binned[j];
    if (j + 4 < en) rec1 = binned[j + 4];
    if (j < en)     hv0 = hsl[(size_t)(rec0.x & 0xFFFF) * NHID];
    while (j < en) {
        int jn = j + 4;
        short hv1 = 0; int2 rec2 = {0,0};
        if (jn < en)     hv1 = hsl[(size_t)(rec1.x & 0xFFFF) * NHID];
        if (jn + 4 < en) rec2 = binned[jn + 4];
        float w = bf2f((short)((unsigned)rec0.x >> 16));
        atomicAdd(&acc[rec0.y * 64 + lane], w * bf2f(hv0));
        rec0 = rec1; rec1 = rec2; hv0 = hv1; j = jn;
    }
    __syncthreads();
    for (int r = wv; r < BKT; r += 4)
        agg0[(size_t)(b * BKT + r) * NHID + sl * 64 + lane] = acc[r * 64 + lane];
}

// ---------------- GEMM2 (MFMA): h2 = relu(agg0 + b1) @ W2, bf16 out ------------------
__global__ __launch_bounds__(256) void gemm2_mfma_kernel(const float* __restrict__ agg0,
                                                         const float* __restrict__ b1,
                                                         const short* __restrict__ W2t,
                                                         short* __restrict__ h2b) {
    __shared__ short Bs[64 * 264];
    __shared__ short As[64 * 32];
    const int tid  = threadIdx.x;
    const int wave = tid >> 6, lane = tid & 63;
    const int mlo  = lane & 15, q = lane >> 4;
    const int m0   = blockIdx.x * 64;

    {
        int n = tid >> 2, seg = (tid & 3) * 64;
        #pragma unroll
        for (int i = 0; i < 8; ++i)
            *(short8*)&Bs[n * 264 + seg + i * 8] =
                *(const short8*)(W2t + n * NHID + seg + i * 8);
    }

    const int ar  = tid >> 2;
    const int acg = (tid & 3) * 8;
    int arow = m0 + ar; if (arow >= N_NODES) arow = N_NODES - 1;
    const float* aptr = agg0 + (size_t)arow * NHID + acg;

    floatx4 acc[4] = {};

    for (int kc = 0; kc < NHID; kc += 32) {
        float4 a0 = *(const float4*)(aptr + kc);
        float4 a1 = *(const float4*)(aptr + kc + 4);
        float4 c0 = *(const float4*)(b1 + kc + acg);
        float4 c1 = *(const float4*)(b1 + kc + acg + 4);
        float v0 = a0.x + c0.x, v1 = a0.y + c0.y, v2 = a0.z + c0.z, v3 = a0.w + c0.w;
        float v4 = a1.x + c1.x, v5 = a1.y + c1.y, v6 = a1.z + c1.z, v7 = a1.w + c1.w;
        short8 apk;
        apk[0] = f2bf(v0 > 0.f ? v0 : 0.f); apk[1] = f2bf(v1 > 0.f ? v1 : 0.f);
        apk[2] = f2bf(v2 > 0.f ? v2 : 0.f); apk[3] = f2bf(v3 > 0.f ? v3 : 0.f);
        apk[4] = f2bf(v4 > 0.f ? v4 : 0.f); apk[5] = f2bf(v5 > 0.f ? v5 : 0.f);
        apk[6] = f2bf(v6 > 0.f ? v6 : 0.f); apk[7] = f2bf(v7 > 0.f ? v7 : 0.f);
        *(short8*)&As[ar * 32 + acg] = apk;
        __syncthreads();

        short8 af = *(const short8*)&As[(wave * 16 + mlo) * 32 + q * 8];
        #pragma unroll
        for (int u = 0; u < 4; ++u) {
            short8 bfr = *(const short8*)&Bs[(u * 16 + mlo) * 264 + kc + q * 8];
            acc[u] = __builtin_amdgcn_mfma_f32_16x16x32_bf16(af, bfr, acc[u], 0, 0, 0);
        }
        __syncthreads();
    }

    #pragma unroll
    for (int r = 0; r < 4; ++r) {
        int row = m0 + wave * 16 + q * 4 + r;
        if (row < N_NODES)
            #pragma unroll
            for (int u = 0; u < 4; ++u)
                h2b[(size_t)row * NCLASS + u * 16 + mlo] = f2bf(acc[u][r]);
    }
}

// ---------------- SpMM2 + bias + log_softmax: block per bucket, LDS accumulator ------
__global__ __launch_bounds__(256) void spmm2_lsm_bucket_kernel(const int* __restrict__ base,
                                                               const int2* __restrict__ binned,
                                                               const short* __restrict__ h2b,
                                                               const float* __restrict__ b2,
                                                               float* __restrict__ out) {
    __shared__ float acc[BKT * 64];   // 20 KB
    const int b = blockIdx.x;         // 0..624
    const int tid = threadIdx.x, lane = tid & 63, wv = tid >> 6;
    for (int t = tid; t < BKT * 64; t += 256) acc[t] = 0.f;
    __syncthreads();

    const int st = base[b], en = base[b + 1];
    const short* hsl = h2b + lane;

    int j = st + wv;
    int2 rec0 = {0,0}, rec1 = {0,0};
    short hv0 = 0;
    if (j < en)     rec0 = binned[j];
    if (j + 4 < en) rec1 = binned[j + 4];
    if (j < en)     hv0 = hsl[(size_t)(rec0.x & 0xFFFF) * NCLASS];
    while (j < en) {
        int jn = j + 4;
        short hv1 = 0; int2 rec2 = {0,0};
        if (jn < en)     hv1 = hsl[(size_t)(rec1.x & 0xFFFF) * NCLASS];
        if (jn + 4 < en) rec2 = binned[jn + 4];
        float w = bf2f((short)((unsigned)rec0.x >> 16));
        atomicAdd(&acc[rec0.y * 64 + lane], w * bf2f(hv0));
        rec0 = rec1; rec1 = rec2; hv0 = hv1; j = jn;
    }
    __syncthreads();

    const float bias = b2[lane];
    for (int r = wv; r < BKT; r += 4) {
        float v = acc[r * 64 + lane] + bias;
        float m = v;
        #pragma unroll
        for (int off = 32; off > 0; off >>= 1) m = fmaxf(m, __shfl_xor(m, off, 64));
        float s = __expf(v - m);
        #pragma unroll
        for (int off = 32; off > 0; off >>= 1) s += __shfl_xor(s, off, 64);
        out[(size_t)(b * BKT + r) * NCLASS + lane] = v - m - __logf(s);
    }
}

extern "C" void kernel_launch(void* const* d_in, const int* in_sizes, int n_in,
                              void* d_out, int out_size, void* d_ws, size_t ws_size,
                              hipStream_t stream) {
    const float* x   = (const float*)d_in[0];
    const int*   es0 = (const int*)  d_in[1];
    const int*   ed0 = (const int*)  d_in[2];
    const float* ew0 = (const float*)d_in[3];
    const int*   es1 = (const int*)  d_in[4];
    const int*   ed1 = (const int*)  d_in[5];
    const float* ew1 = (const float*)d_in[6];
    const float* W1  = (const float*)d_in[7];
    const float* b1  = (const float*)d_in[8];
    const float* W2  = (const float*)d_in[9];
    const float* b2  = (const float*)d_in[10];
    float* out = (float*)d_out;

    // ws layout (bytes):
    //   [0, 25.6e6):        h0b bf16 [50000x256]; later h2b bf16 [50000x64] at [0,6.4e6)
    //   [25.6e6, 32.0e6):   binned1 (800000 x int2)
    //   [32.0e6, 32.64e6):  hist  [2][128][625] int
    //   [32.64e6, 33.28e6): offT  [2][625][128] int
    //   [33.28e6, +5KB):    tot   [2][625] int
    //   [33.29e6, +5KB):    base  [2][626] int
    //   [51.2e6, 102.4e6):  agg0 fp32 [50000x256]
    char* ws = (char*)d_ws;
    short* h0b    = (short*)ws;
    short* h2b    = (short*)ws;
    int2*  binned1= (int2*)(ws + 25600000);
    int*   hist   = (int*)(ws + 32000000);
    int*   offT   = (int*)(ws + 32640000);
    int*   tot    = (int*)(ws + 33280000);
    int*   basep  = (int*)(ws + 33290000);
    float* agg0   = (float*)(ws + 51200000);

    // d_out scratch (12.8e6 B; everything dead before the final kernel overwrites it):
    //   [0, 6.4e6): binned0;  [8MiB,+512KB): Wt;  [9MiB,+64KB): W2t
    int2*  binned0 = (int2*)d_out;
    short* Wt      = (short*)((char*)d_out + (8u << 20));
    short* W2t     = (short*)((char*)d_out + (9u << 20));

    // ---- bucket binning (no device-scope atomics, no memsets) ----
    bh_kernel<<<2 * NBB, 256, 0, stream>>>(ed0, ed1, hist);
    bscan_kernel<<<2 * NB, 256, 0, stream>>>(hist, offT, tot);
    btop_kernel<<<2, 256, 0, stream>>>(tot, basep);
    bscatter_kernel<<<2 * NBB, 256, 0, stream>>>(es0, ed0, ew0, es1, ed1, ew1,
                                                 offT, basep, binned0, binned1);

    // ---- weights ----
    cast_w1t_kernel<<<NFEAT, 256, 0, stream>>>(W1, Wt);
    cast_w2t_kernel<<<NCLASS, 256, 0, stream>>>(W2, W2t);

    // ---- layer 1 ----
    gemm1_mfma_kernel<<<MTILES, 256, 0, stream>>>(x, Wt, h0b);
    spmm1_bucket_kernel<<<NB * 4, 256, 0, stream>>>(basep, binned0, h0b, agg0);

    // ---- layer 2 (spmm2 fused with bias + log_softmax, writes out directly) ----
    gemm2_mfma_kernel<<<MTILES, 256, 0, stream>>>(agg0, b1, W2t, h2b);
    spmm2_lsm_bucket_kernel<<<NB, 256, 0, stream>>>(basep + (NB + 1), binned1, h2b, b2, out);
}